// Round 1
// baseline (531.031 us; speedup 1.0000x reference)
//
#include <hip/hip_runtime.h>
#include <hip/hip_bf16.h>
#include <math.h>

// Problem constants: B=1, N=4096, C=768, H=12, HD=64
#define LOG2E 1.44269504088896340736f

typedef short bf16x8 __attribute__((ext_vector_type(8)));
typedef float f32x4 __attribute__((ext_vector_type(4)));

static __device__ __forceinline__ float bf2f(ushort u){
  union { float f; unsigned int u; } x; x.u = ((unsigned int)u) << 16; return x.f;
}
static __device__ __forceinline__ ushort f2bf(float f){
  union { float f; unsigned int u; } x; x.f = f;
  unsigned int r = x.u + 0x7fffu + ((x.u >> 16) & 1u);   // RNE
  return (ushort)(r >> 16);
}

// ---------------- fp32 -> bf16 weight conversion ----------------
__global__ __launch_bounds__(256) void cvt_f32_bf16(const float* __restrict__ src,
                                                    ushort* __restrict__ dst, int n4){
  int i = blockIdx.x * 256 + threadIdx.x;
  if (i < n4){
    float4 v = ((const float4*)src)[i];
    ushort4 o;
    o.x = f2bf(v.x); o.y = f2bf(v.y); o.z = f2bf(v.z); o.w = f2bf(v.w);
    ((ushort4*)dst)[i] = o;
  }
}

// ---------------- LayerNorm (fp32 in -> bf16 out), one block per row of 768 ----------------
__device__ __forceinline__ float block_sum256(float s, float* red){
  #pragma unroll
  for (int off = 32; off; off >>= 1) s += __shfl_xor(s, off, 64);
  int w = threadIdx.x >> 6;
  if ((threadIdx.x & 63) == 0) red[w] = s;
  __syncthreads();
  float tot = red[0] + red[1] + red[2] + red[3];
  __syncthreads();
  return tot;
}

__global__ __launch_bounds__(256) void ln_kernel(const float* __restrict__ x,
                                                 const float* __restrict__ g,
                                                 const float* __restrict__ bta,
                                                 ushort* __restrict__ out){
  __shared__ float red[4];
  int row = blockIdx.x, t = threadIdx.x;
  const float* xr = x + (size_t)row * 768;
  float v0 = xr[t], v1 = xr[t + 256], v2 = xr[t + 512];
  float mu = block_sum256(v0 + v1 + v2, red) * (1.0f / 768.0f);
  float d0 = v0 - mu, d1 = v1 - mu, d2 = v2 - mu;
  float var = block_sum256(d0*d0 + d1*d1 + d2*d2, red) * (1.0f / 768.0f);
  float rs = rsqrtf(var + 1e-5f);
  ushort* orow = out + (size_t)row * 768;
  orow[t]       = f2bf(d0 * rs * g[t]       + bta[t]);
  orow[t + 256] = f2bf(d1 * rs * g[t + 256] + bta[t + 256]);
  orow[t + 512] = f2bf(d2 * rs * g[t + 512] + bta[t + 512]);
}

// ---------------- generic bf16 MFMA GEMM: C[M,N] = A[M,K] * B[N,K]^T ----------------
// 128x128 block tile, BK=64, 4 waves (2x2), each wave 64x64 (4x4 frags of 16x16x32).
// MODE 0: store bf16(C).  MODE 1: store fp32(C + bias + res).  MODE 2: store bf16(gelu(C + bias)).
template<int MODE>
__global__ __launch_bounds__(256) void gemm_bf16(const ushort* __restrict__ A, int lda,
                                                 const ushort* __restrict__ Bm, int ldb,
                                                 int K,
                                                 const float* __restrict__ bias,
                                                 const float* __restrict__ res, int ldr,
                                                 void* __restrict__ out, int ldo){
  __shared__ ushort As[128 * 64];
  __shared__ ushort Bs[128 * 64];
  const int tid = threadIdx.x;
  const int m0 = blockIdx.x * 128, n0 = blockIdx.y * 128;
  const int w = tid >> 6, l = tid & 63;
  const int wm = (w >> 1) * 64, wn = (w & 1) * 64;
  const int lr = l & 15, lg = l >> 4;

  f32x4 acc[4][4] = {};

  for (int k0 = 0; k0 < K; k0 += 64){
    #pragma unroll
    for (int it = 0; it < 4; ++it){
      int idx = it * 256 + tid;
      int row = idx >> 3, cg = idx & 7;
      // XOR-swizzled LDS store (col-group ^= row&7) to kill stride-128B bank conflicts on reads
      bf16x8 va = *(const bf16x8*)(A + (size_t)(m0 + row) * lda + k0 + cg * 8);
      *(bf16x8*)(As + row * 64 + ((cg ^ (row & 7)) * 8)) = va;
      bf16x8 vb = *(const bf16x8*)(Bm + (size_t)(n0 + row) * ldb + k0 + cg * 8);
      *(bf16x8*)(Bs + row * 64 + ((cg ^ (row & 7)) * 8)) = vb;
    }
    __syncthreads();
    #pragma unroll
    for (int kk = 0; kk < 2; ++kk){
      bf16x8 af[4], bfr[4];
      #pragma unroll
      for (int mi = 0; mi < 4; ++mi){
        int row = wm + mi * 16 + lr;
        int cg = (kk * 4 + lg) ^ (row & 7);
        af[mi] = *(const bf16x8*)(As + row * 64 + cg * 8);
      }
      #pragma unroll
      for (int nj = 0; nj < 4; ++nj){
        int row = wn + nj * 16 + lr;
        int cg = (kk * 4 + lg) ^ (row & 7);
        bfr[nj] = *(const bf16x8*)(Bs + row * 64 + cg * 8);
      }
      #pragma unroll
      for (int mi = 0; mi < 4; ++mi)
        #pragma unroll
        for (int nj = 0; nj < 4; ++nj)
          acc[mi][nj] = __builtin_amdgcn_mfma_f32_16x16x32_bf16(af[mi], bfr[nj], acc[mi][nj], 0, 0, 0);
    }
    __syncthreads();
  }

  // epilogue: D layout row=(lane>>4)*4+reg, col=lane&15 (m89-verified)
  #pragma unroll
  for (int mi = 0; mi < 4; ++mi){
    #pragma unroll
    for (int nj = 0; nj < 4; ++nj){
      #pragma unroll
      for (int r = 0; r < 4; ++r){
        int grow = m0 + wm + mi * 16 + lg * 4 + r;
        int gcol = n0 + wn + nj * 16 + lr;
        float v = acc[mi][nj][r];
        if (MODE == 0){
          ((ushort*)out)[(size_t)grow * ldo + gcol] = f2bf(v);
        } else if (MODE == 1){
          v += bias[gcol] + res[(size_t)grow * ldr + gcol];
          ((float*)out)[(size_t)grow * ldo + gcol] = v;
        } else {
          v += bias[gcol];
          v = 0.5f * v * (1.0f + erff(v * 0.70710678118654752f));  // exact GELU
          ((ushort*)out)[(size_t)grow * ldo + gcol] = f2bf(v);
        }
      }
    }
  }
}

// ---------------- RoPE + QKV reshape: qkv[n][3][h][d] -> Qs/Ks [h][n][d], Vt [h][d][n] ----------------
// Q gets the 1/sqrt(HD)=0.125 scale folded in (exact pow2, lossless in bf16).
__global__ __launch_bounds__(384) void rope_kernel(const ushort* __restrict__ qkv,
                                                   const float* __restrict__ fc,
                                                   const float* __restrict__ fs,
                                                   ushort* __restrict__ Qs,
                                                   ushort* __restrict__ Ks,
                                                   ushort* __restrict__ Vt){
  int n = blockIdx.x, t = threadIdx.x;
  int h = t >> 5, p = t & 31;
  float c = fc[(size_t)n * 32 + p], s = fs[(size_t)n * 32 + p];
  const ushort* row = qkv + (size_t)n * 2304;
  {
    float t0 = bf2f(row[h * 64 + 2 * p]), t1 = bf2f(row[h * 64 + 2 * p + 1]);
    ushort* dst = Qs + ((size_t)h * 4096 + n) * 64;
    dst[2 * p]     = f2bf((t0 * c - t1 * s) * 0.125f);
    dst[2 * p + 1] = f2bf((t0 * s + t1 * c) * 0.125f);
  }
  {
    float t0 = bf2f(row[768 + h * 64 + 2 * p]), t1 = bf2f(row[768 + h * 64 + 2 * p + 1]);
    ushort* dst = Ks + ((size_t)h * 4096 + n) * 64;
    dst[2 * p]     = f2bf(t0 * c - t1 * s);
    dst[2 * p + 1] = f2bf(t0 * s + t1 * c);
  }
  #pragma unroll
  for (int i = 0; i < 2; ++i){
    int idx = t + i * 384;
    int hh = idx >> 6, d = idx & 63;
    Vt[((size_t)hh * 64 + d) * 4096 + n] = row[1536 + idx];
  }
}

// ---------------- flash attention: O[n][h*64+d] = softmax(Q K^T) V ----------------
// grid (N/64, H), 4 waves/block, each wave owns 16 q-rows; 32-key tiles; online softmax.
__global__ __launch_bounds__(256) void flash_attn(const ushort* __restrict__ Qs,
                                                  const ushort* __restrict__ Ks,
                                                  const ushort* __restrict__ Vt,
                                                  ushort* __restrict__ O){
  __shared__ ushort p_lds[4][16 * 40];   // stride 40 elems (80B) -> conflict-free b128 reads
  int h = blockIdx.y;
  int w = threadIdx.x >> 6, l = threadIdx.x & 63;
  int lr = l & 15, lg = l >> 4;
  int q0 = blockIdx.x * 64 + w * 16;
  const ushort* Qh = Qs + (size_t)h * 4096 * 64;
  const ushort* Kh = Ks + (size_t)h * 4096 * 64;
  const ushort* Vh = Vt + (size_t)h * 64 * 4096;

  bf16x8 qa[2];
  #pragma unroll
  for (int kk = 0; kk < 2; ++kk)
    qa[kk] = *(const bf16x8*)(Qh + (size_t)(q0 + lr) * 64 + kk * 32 + lg * 8);

  f32x4 oacc[4] = {};
  float m_prev[4], lsum[4];
  #pragma unroll
  for (int r = 0; r < 4; ++r){ m_prev[r] = -1e30f; lsum[r] = 0.0f; }
  ushort* pl = &p_lds[w][0];

  for (int kb = 0; kb < 4096; kb += 32){
    f32x4 s0 = {}, s1 = {};
    #pragma unroll
    for (int kk = 0; kk < 2; ++kk){
      bf16x8 b0 = *(const bf16x8*)(Kh + (size_t)(kb + lr) * 64 + kk * 32 + lg * 8);
      bf16x8 b1 = *(const bf16x8*)(Kh + (size_t)(kb + 16 + lr) * 64 + kk * 32 + lg * 8);
      s0 = __builtin_amdgcn_mfma_f32_16x16x32_bf16(qa[kk], b0, s0, 0, 0, 0);
      s1 = __builtin_amdgcn_mfma_f32_16x16x32_bf16(qa[kk], b1, s1, 0, 0, 0);
    }
    float pr0[4], pr1[4];
    #pragma unroll
    for (int r = 0; r < 4; ++r){
      float mb = fmaxf(s0[r], s1[r]);
      #pragma unroll
      for (int off = 1; off < 16; off <<= 1) mb = fmaxf(mb, __shfl_xor(mb, off, 64));
      float mn = fmaxf(m_prev[r], mb);
      float scale = exp2f((m_prev[r] - mn) * LOG2E);
      float p0 = exp2f((s0[r] - mn) * LOG2E);
      float p1 = exp2f((s1[r] - mn) * LOG2E);
      float rs = p0 + p1;
      #pragma unroll
      for (int off = 1; off < 16; off <<= 1) rs += __shfl_xor(rs, off, 64);
      lsum[r] = lsum[r] * scale + rs;
      m_prev[r] = mn;
      pr0[r] = p0; pr1[r] = p1;
      #pragma unroll
      for (int db = 0; db < 4; ++db) oacc[db][r] *= scale;
    }
    #pragma unroll
    for (int r = 0; r < 4; ++r){
      pl[(lg * 4 + r) * 40 + lr]      = f2bf(pr0[r]);
      pl[(lg * 4 + r) * 40 + 16 + lr] = f2bf(pr1[r]);
    }
    __syncthreads();
    bf16x8 pf = *(const bf16x8*)(pl + lr * 40 + lg * 8);
    #pragma unroll
    for (int db = 0; db < 4; ++db){
      bf16x8 vf = *(const bf16x8*)(Vh + (size_t)(db * 16 + lr) * 4096 + kb + lg * 8);
      oacc[db] = __builtin_amdgcn_mfma_f32_16x16x32_bf16(pf, vf, oacc[db], 0, 0, 0);
    }
    __syncthreads();
  }

  #pragma unroll
  for (int db = 0; db < 4; ++db){
    float inv;
    #pragma unroll
    for (int r = 0; r < 4; ++r){
      inv = 1.0f / lsum[r];
      int rowi = q0 + lg * 4 + r;
      O[(size_t)rowi * 768 + h * 64 + db * 16 + lr] = f2bf(oacc[db][r] * inv);
    }
  }
}

// ---------------- launch ----------------
extern "C" void kernel_launch(void* const* d_in, const int* in_sizes, int n_in,
                              void* d_out, int out_size, void* d_ws, size_t ws_size,
                              hipStream_t stream){
  const float* x      = (const float*)d_in[0];
  const float* fcos   = (const float*)d_in[1];
  const float* fsin   = (const float*)d_in[2];
  const float* w_qkv  = (const float*)d_in[3];
  const float* w_proj = (const float*)d_in[4];
  const float* b_proj = (const float*)d_in[5];
  const float* g1     = (const float*)d_in[6];
  const float* beta1  = (const float*)d_in[7];
  const float* g2     = (const float*)d_in[8];
  const float* beta2  = (const float*)d_in[9];
  const float* w_fc1  = (const float*)d_in[10];
  const float* b_fc1  = (const float*)d_in[11];
  const float* w_fc2  = (const float*)d_in[12];
  const float* b_fc2  = (const float*)d_in[13];

  char* ws = (char*)d_ws;
  size_t off = 0;
  auto alloc = [&](size_t bytes) -> char* {
    char* p = ws + off; off += (bytes + 255) & ~(size_t)255; return p;
  };
  ushort* wq  = (ushort*)alloc((size_t)2304 * 768 * 2);
  ushort* wp  = (ushort*)alloc((size_t)768 * 768 * 2);
  ushort* w1  = (ushort*)alloc((size_t)3072 * 768 * 2);
  ushort* w2  = (ushort*)alloc((size_t)768 * 3072 * 2);
  ushort* h1  = (ushort*)alloc((size_t)4096 * 768 * 2);
  ushort* qkv = (ushort*)alloc((size_t)4096 * 2304 * 2);
  ushort* Qs  = (ushort*)alloc((size_t)12 * 4096 * 64 * 2);
  ushort* Ks  = (ushort*)alloc((size_t)12 * 4096 * 64 * 2);
  ushort* Vt  = (ushort*)alloc((size_t)12 * 64 * 4096 * 2);
  ushort* ao  = (ushort*)alloc((size_t)4096 * 768 * 2);
  float*  x2  = (float*) alloc((size_t)4096 * 768 * 4);
  ushort* h2  = (ushort*)alloc((size_t)4096 * 768 * 2);
  ushort* f1  = (ushort*)alloc((size_t)4096 * 3072 * 2);

  // weights -> bf16
  cvt_f32_bf16<<<(2304*768/4 + 255)/256, 256, 0, stream>>>(w_qkv,  wq, 2304*768/4);
  cvt_f32_bf16<<<(768*768/4  + 255)/256, 256, 0, stream>>>(w_proj, wp, 768*768/4);
  cvt_f32_bf16<<<(3072*768/4 + 255)/256, 256, 0, stream>>>(w_fc1,  w1, 3072*768/4);
  cvt_f32_bf16<<<(768*3072/4 + 255)/256, 256, 0, stream>>>(w_fc2,  w2, 768*3072/4);

  // LN1
  ln_kernel<<<4096, 256, 0, stream>>>(x, g1, beta1, h1);
  // QKV: [4096,2304] = h1[4096,768] @ w_qkv[2304,768]^T
  gemm_bf16<0><<<dim3(32, 18), 256, 0, stream>>>(h1, 768, wq, 768, 768,
                                                 nullptr, nullptr, 0, qkv, 2304);
  // RoPE + per-head layouts
  rope_kernel<<<4096, 384, 0, stream>>>(qkv, fcos, fsin, Qs, Ks, Vt);
  // attention
  flash_attn<<<dim3(64, 12), 256, 0, stream>>>(Qs, Ks, Vt, ao);
  // proj + residual: x2 = x + ao @ w_proj^T + b_proj  (fp32)
  gemm_bf16<1><<<dim3(32, 6), 256, 0, stream>>>(ao, 768, wp, 768, 768,
                                                b_proj, x, 768, x2, 768);
  // LN2
  ln_kernel<<<4096, 256, 0, stream>>>(x2, g2, beta2, h2);
  // fc1 + GELU: f1 = gelu(h2 @ w_fc1^T + b_fc1)  (bf16)
  gemm_bf16<2><<<dim3(32, 24), 256, 0, stream>>>(h2, 768, w1, 768, 768,
                                                 b_fc1, nullptr, 0, f1, 3072);
  // fc2 + residual: out = x2 + f1 @ w_fc2^T + b_fc2  (fp32)
  gemm_bf16<1><<<dim3(32, 6), 256, 0, stream>>>(f1, 3072, w2, 3072, 3072,
                                                b_fc2, x2, 768, (float*)d_out, 768);
}

// Round 2
// 525.670 us; speedup vs baseline: 1.0102x; 1.0102x over previous
//
#include <hip/hip_runtime.h>
#include <hip/hip_bf16.h>
#include <math.h>

// Problem constants: B=1, N=4096, C=768, H=12, HD=64
#define LOG2E 1.44269504088896340736f

typedef short bf16x8 __attribute__((ext_vector_type(8)));
typedef float f32x4 __attribute__((ext_vector_type(4)));

static __device__ __forceinline__ float bf2f(ushort u){
  union { float f; unsigned int u; } x; x.u = ((unsigned int)u) << 16; return x.f;
}
static __device__ __forceinline__ ushort f2bf(float f){
  union { float f; unsigned int u; } x; x.f = f;
  unsigned int r = x.u + 0x7fffu + ((x.u >> 16) & 1u);   // RNE
  return (ushort)(r >> 16);
}
static __device__ __forceinline__ unsigned cvt_pk_bf16(float a, float b){
  unsigned r;
  asm("v_cvt_pk_bf16_f32 %0, %1, %2" : "=v"(r) : "v"(a), "v"(b));
  return r;   // lo = bf16(a), hi = bf16(b)
}

// ---------------- fp32 -> bf16 weight conversion ----------------
__global__ __launch_bounds__(256) void cvt_f32_bf16(const float* __restrict__ src,
                                                    ushort* __restrict__ dst, int n4){
  int i = blockIdx.x * 256 + threadIdx.x;
  if (i < n4){
    float4 v = ((const float4*)src)[i];
    ushort4 o;
    o.x = f2bf(v.x); o.y = f2bf(v.y); o.z = f2bf(v.z); o.w = f2bf(v.w);
    ((ushort4*)dst)[i] = o;
  }
}

// ---------------- LayerNorm (fp32 in -> bf16 out), one block per row of 768 ----------------
__device__ __forceinline__ float block_sum256(float s, float* red){
  #pragma unroll
  for (int off = 32; off; off >>= 1) s += __shfl_xor(s, off, 64);
  int w = threadIdx.x >> 6;
  if ((threadIdx.x & 63) == 0) red[w] = s;
  __syncthreads();
  float tot = red[0] + red[1] + red[2] + red[3];
  __syncthreads();
  return tot;
}

__global__ __launch_bounds__(256) void ln_kernel(const float* __restrict__ x,
                                                 const float* __restrict__ g,
                                                 const float* __restrict__ bta,
                                                 ushort* __restrict__ out){
  __shared__ float red[4];
  int row = blockIdx.x, t = threadIdx.x;
  const float* xr = x + (size_t)row * 768;
  float v0 = xr[t], v1 = xr[t + 256], v2 = xr[t + 512];
  float mu = block_sum256(v0 + v1 + v2, red) * (1.0f / 768.0f);
  float d0 = v0 - mu, d1 = v1 - mu, d2 = v2 - mu;
  float var = block_sum256(d0*d0 + d1*d1 + d2*d2, red) * (1.0f / 768.0f);
  float rs = rsqrtf(var + 1e-5f);
  ushort* orow = out + (size_t)row * 768;
  orow[t]       = f2bf(d0 * rs * g[t]       + bta[t]);
  orow[t + 256] = f2bf(d1 * rs * g[t + 256] + bta[t + 256]);
  orow[t + 512] = f2bf(d2 * rs * g[t + 512] + bta[t + 512]);
}

// ---------------- generic bf16 MFMA GEMM: C[M,N] = A[M,K] * B[N,K]^T ----------------
// 128x128 block tile, BK=64, 4 waves (2x2), each wave 64x64 (4x4 frags of 16x16x32).
// MODE 0: store bf16(C).  MODE 1: store fp32(C + bias + res).  MODE 2: store bf16(gelu(C + bias)).
template<int MODE>
__global__ __launch_bounds__(256) void gemm_bf16(const ushort* __restrict__ A, int lda,
                                                 const ushort* __restrict__ Bm, int ldb,
                                                 int K,
                                                 const float* __restrict__ bias,
                                                 const float* __restrict__ res, int ldr,
                                                 void* __restrict__ out, int ldo){
  __shared__ ushort As[128 * 64];
  __shared__ ushort Bs[128 * 64];
  const int tid = threadIdx.x;
  const int m0 = blockIdx.x * 128, n0 = blockIdx.y * 128;
  const int w = tid >> 6, l = tid & 63;
  const int wm = (w >> 1) * 64, wn = (w & 1) * 64;
  const int lr = l & 15, lg = l >> 4;

  f32x4 acc[4][4] = {};

  for (int k0 = 0; k0 < K; k0 += 64){
    #pragma unroll
    for (int it = 0; it < 4; ++it){
      int idx = it * 256 + tid;
      int row = idx >> 3, cg = idx & 7;
      // XOR-swizzled LDS store (col-group ^= row&7) to kill stride-128B bank conflicts on reads
      bf16x8 va = *(const bf16x8*)(A + (size_t)(m0 + row) * lda + k0 + cg * 8);
      *(bf16x8*)(As + row * 64 + ((cg ^ (row & 7)) * 8)) = va;
      bf16x8 vb = *(const bf16x8*)(Bm + (size_t)(n0 + row) * ldb + k0 + cg * 8);
      *(bf16x8*)(Bs + row * 64 + ((cg ^ (row & 7)) * 8)) = vb;
    }
    __syncthreads();
    #pragma unroll
    for (int kk = 0; kk < 2; ++kk){
      bf16x8 af[4], bfr[4];
      #pragma unroll
      for (int mi = 0; mi < 4; ++mi){
        int row = wm + mi * 16 + lr;
        int cg = (kk * 4 + lg) ^ (row & 7);
        af[mi] = *(const bf16x8*)(As + row * 64 + cg * 8);
      }
      #pragma unroll
      for (int nj = 0; nj < 4; ++nj){
        int row = wn + nj * 16 + lr;
        int cg = (kk * 4 + lg) ^ (row & 7);
        bfr[nj] = *(const bf16x8*)(Bs + row * 64 + cg * 8);
      }
      #pragma unroll
      for (int mi = 0; mi < 4; ++mi)
        #pragma unroll
        for (int nj = 0; nj < 4; ++nj)
          acc[mi][nj] = __builtin_amdgcn_mfma_f32_16x16x32_bf16(af[mi], bfr[nj], acc[mi][nj], 0, 0, 0);
    }
    __syncthreads();
  }

  // epilogue: D layout row=(lane>>4)*4+reg, col=lane&15 (m89-verified)
  #pragma unroll
  for (int mi = 0; mi < 4; ++mi){
    #pragma unroll
    for (int nj = 0; nj < 4; ++nj){
      #pragma unroll
      for (int r = 0; r < 4; ++r){
        int grow = m0 + wm + mi * 16 + lg * 4 + r;
        int gcol = n0 + wn + nj * 16 + lr;
        float v = acc[mi][nj][r];
        if (MODE == 0){
          ((ushort*)out)[(size_t)grow * ldo + gcol] = f2bf(v);
        } else if (MODE == 1){
          v += bias[gcol] + res[(size_t)grow * ldr + gcol];
          ((float*)out)[(size_t)grow * ldo + gcol] = v;
        } else {
          v += bias[gcol];
          v = 0.5f * v * (1.0f + erff(v * 0.70710678118654752f));  // exact GELU
          ((ushort*)out)[(size_t)grow * ldo + gcol] = f2bf(v);
        }
      }
    }
  }
}

// ---------------- RoPE + QKV reshape: qkv[n][3][h][d] -> Qs/Ks [h][n][d], Vt [h][d][n] ----------------
// Q gets 1/sqrt(HD) * LOG2E folded in (flash softmax works in the exp2 domain).
__global__ __launch_bounds__(384) void rope_kernel(const ushort* __restrict__ qkv,
                                                   const float* __restrict__ fc,
                                                   const float* __restrict__ fs,
                                                   ushort* __restrict__ Qs,
                                                   ushort* __restrict__ Ks,
                                                   ushort* __restrict__ Vt){
  int n = blockIdx.x, t = threadIdx.x;
  int h = t >> 5, p = t & 31;
  float c = fc[(size_t)n * 32 + p], s = fs[(size_t)n * 32 + p];
  const ushort* row = qkv + (size_t)n * 2304;
  const float qscale = 0.125f * LOG2E;
  {
    float t0 = bf2f(row[h * 64 + 2 * p]), t1 = bf2f(row[h * 64 + 2 * p + 1]);
    ushort* dst = Qs + ((size_t)h * 4096 + n) * 64;
    dst[2 * p]     = f2bf((t0 * c - t1 * s) * qscale);
    dst[2 * p + 1] = f2bf((t0 * s + t1 * c) * qscale);
  }
  {
    float t0 = bf2f(row[768 + h * 64 + 2 * p]), t1 = bf2f(row[768 + h * 64 + 2 * p + 1]);
    ushort* dst = Ks + ((size_t)h * 4096 + n) * 64;
    dst[2 * p]     = f2bf(t0 * c - t1 * s);
    dst[2 * p + 1] = f2bf(t0 * s + t1 * c);
  }
  #pragma unroll
  for (int i = 0; i < 2; ++i){
    int idx = t + i * 384;
    int hh = idx >> 6, d = idx & 63;
    Vt[((size_t)hh * 64 + d) * 4096 + n] = row[1536 + idx];
  }
}

// ---------------- flash attention, swapped-QK^T in-register softmax ----------------
// grid (N/64, H), 4 waves/block, each wave owns 16 q-rows (q = q0 + (lane&15)).
// S^T = mfma(K_perm, Q): lane (lr,lg) holds keys {32(t>>1)+4(t&1)+8lg+r} for q=lr,
// which after cvt_pk IS the PV B-fragment (k = 8*lg + j) — no LDS, no shuffles.
__global__ __launch_bounds__(256) void flash_attn(const ushort* __restrict__ Qs,
                                                  const ushort* __restrict__ Ks,
                                                  const ushort* __restrict__ Vt,
                                                  ushort* __restrict__ O){
  int h = blockIdx.y;
  int w = threadIdx.x >> 6, l = threadIdx.x & 63;
  int lr = l & 15, lg = l >> 4;
  int q0 = blockIdx.x * 64 + w * 16;
  const ushort* Qh = Qs + (size_t)h * (4096 * 64);
  const ushort* Kh = Ks + (size_t)h * (4096 * 64);
  const ushort* Vh = Vt + (size_t)h * (64 * 4096);

  bf16x8 qa[2];
  #pragma unroll
  for (int kk = 0; kk < 2; ++kk)
    qa[kk] = *(const bf16x8*)(Qh + (size_t)(q0 + lr) * 64 + kk * 32 + lg * 8);

  f32x4 oacc[4] = {};            // C[d = db*16 + 4lg + r][q = lr]
  float m_prev = -1e30f, lsum = 0.0f;
  const int krow = 8 * (lr >> 2) + (lr & 3);   // permuted K-row base

  for (int kb = 0; kb < 4096; kb += 64){
    f32x4 s[4] = {};
    #pragma unroll
    for (int t = 0; t < 4; ++t){
      const ushort* kp = Kh + (size_t)(kb + krow + 32 * (t >> 1) + 4 * (t & 1)) * 64 + lg * 8;
      bf16x8 k0 = *(const bf16x8*)(kp);
      bf16x8 k1 = *(const bf16x8*)(kp + 32);
      s[t] = __builtin_amdgcn_mfma_f32_16x16x32_bf16(k0, qa[0], s[t], 0, 0, 0);
      s[t] = __builtin_amdgcn_mfma_f32_16x16x32_bf16(k1, qa[1], s[t], 0, 0, 0);
    }
    // row max over this lane's 16 keys, then across the 4 lg-groups (same q = lr)
    float mb = -1e30f;
    #pragma unroll
    for (int r = 0; r < 4; ++r)
      mb = fmaxf(mb, fmaxf(fmaxf(s[0][r], s[1][r]), fmaxf(s[2][r], s[3][r])));
    mb = fmaxf(mb, __shfl_xor(mb, 16, 64));
    mb = fmaxf(mb, __shfl_xor(mb, 32, 64));
    bool defer = (mb - m_prev) <= 8.0f;          // log2 units; P bounded by 256
    float mn = defer ? m_prev : mb;
    if (!__all(defer)){
      float sc = exp2f(m_prev - mn);             // ==1 for deferred lanes
      lsum *= sc;
      #pragma unroll
      for (int db = 0; db < 4; ++db)
        #pragma unroll
        for (int r = 0; r < 4; ++r) oacc[db][r] *= sc;
      m_prev = mn;
    }
    float ps = 0.0f;
    #pragma unroll
    for (int t = 0; t < 4; ++t)
      #pragma unroll
      for (int r = 0; r < 4; ++r){
        float pv = exp2f(s[t][r] - mn);          // Q pre-scaled by log2e
        s[t][r] = pv; ps += pv;
      }
    lsum += ps;                                  // per-lane partial; reduced at end
    #pragma unroll
    for (int kk = 0; kk < 2; ++kk){
      union { unsigned u[4]; bf16x8 v; } pf;
      pf.u[0] = cvt_pk_bf16(s[2*kk][0],   s[2*kk][1]);
      pf.u[1] = cvt_pk_bf16(s[2*kk][2],   s[2*kk][3]);
      pf.u[2] = cvt_pk_bf16(s[2*kk+1][0], s[2*kk+1][1]);
      pf.u[3] = cvt_pk_bf16(s[2*kk+1][2], s[2*kk+1][3]);
      #pragma unroll
      for (int db = 0; db < 4; ++db){
        bf16x8 vf = *(const bf16x8*)(Vh + (size_t)(db * 16 + lr) * 4096 + kb + kk * 32 + lg * 8);
        oacc[db] = __builtin_amdgcn_mfma_f32_16x16x32_bf16(vf, pf.v, oacc[db], 0, 0, 0);
      }
    }
  }

  lsum += __shfl_xor(lsum, 16, 64);
  lsum += __shfl_xor(lsum, 32, 64);
  float inv = 1.0f / lsum;
  #pragma unroll
  for (int db = 0; db < 4; ++db){
    unsigned o0 = cvt_pk_bf16(oacc[db][0] * inv, oacc[db][1] * inv);
    unsigned o1 = cvt_pk_bf16(oacc[db][2] * inv, oacc[db][3] * inv);
    uint2 ov; ov.x = o0; ov.y = o1;
    *(uint2*)(O + (size_t)(q0 + lr) * 768 + h * 64 + db * 16 + 4 * lg) = ov;
  }
}

// ---------------- launch ----------------
extern "C" void kernel_launch(void* const* d_in, const int* in_sizes, int n_in,
                              void* d_out, int out_size, void* d_ws, size_t ws_size,
                              hipStream_t stream){
  const float* x      = (const float*)d_in[0];
  const float* fcos   = (const float*)d_in[1];
  const float* fsin   = (const float*)d_in[2];
  const float* w_qkv  = (const float*)d_in[3];
  const float* w_proj = (const float*)d_in[4];
  const float* b_proj = (const float*)d_in[5];
  const float* g1     = (const float*)d_in[6];
  const float* beta1  = (const float*)d_in[7];
  const float* g2     = (const float*)d_in[8];
  const float* beta2  = (const float*)d_in[9];
  const float* w_fc1  = (const float*)d_in[10];
  const float* b_fc1  = (const float*)d_in[11];
  const float* w_fc2  = (const float*)d_in[12];
  const float* b_fc2  = (const float*)d_in[13];

  char* ws = (char*)d_ws;
  size_t off = 0;
  auto alloc = [&](size_t bytes) -> char* {
    char* p = ws + off; off += (bytes + 255) & ~(size_t)255; return p;
  };
  ushort* wq  = (ushort*)alloc((size_t)2304 * 768 * 2);
  ushort* wp  = (ushort*)alloc((size_t)768 * 768 * 2);
  ushort* w1  = (ushort*)alloc((size_t)3072 * 768 * 2);
  ushort* w2  = (ushort*)alloc((size_t)768 * 3072 * 2);
  ushort* h1  = (ushort*)alloc((size_t)4096 * 768 * 2);
  ushort* qkv = (ushort*)alloc((size_t)4096 * 2304 * 2);
  ushort* Qs  = (ushort*)alloc((size_t)12 * 4096 * 64 * 2);
  ushort* Ks  = (ushort*)alloc((size_t)12 * 4096 * 64 * 2);
  ushort* Vt  = (ushort*)alloc((size_t)12 * 64 * 4096 * 2);
  ushort* ao  = (ushort*)alloc((size_t)4096 * 768 * 2);
  float*  x2  = (float*) alloc((size_t)4096 * 768 * 4);
  ushort* h2  = (ushort*)alloc((size_t)4096 * 768 * 2);
  ushort* f1  = (ushort*)alloc((size_t)4096 * 3072 * 2);

  // weights -> bf16
  cvt_f32_bf16<<<(2304*768/4 + 255)/256, 256, 0, stream>>>(w_qkv,  wq, 2304*768/4);
  cvt_f32_bf16<<<(768*768/4  + 255)/256, 256, 0, stream>>>(w_proj, wp, 768*768/4);
  cvt_f32_bf16<<<(3072*768/4 + 255)/256, 256, 0, stream>>>(w_fc1,  w1, 3072*768/4);
  cvt_f32_bf16<<<(768*3072/4 + 255)/256, 256, 0, stream>>>(w_fc2,  w2, 768*3072/4);

  // LN1
  ln_kernel<<<4096, 256, 0, stream>>>(x, g1, beta1, h1);
  // QKV: [4096,2304] = h1[4096,768] @ w_qkv[2304,768]^T
  gemm_bf16<0><<<dim3(32, 18), 256, 0, stream>>>(h1, 768, wq, 768, 768,
                                                 nullptr, nullptr, 0, qkv, 2304);
  // RoPE + per-head layouts
  rope_kernel<<<4096, 384, 0, stream>>>(qkv, fcos, fsin, Qs, Ks, Vt);
  // attention
  flash_attn<<<dim3(64, 12), 256, 0, stream>>>(Qs, Ks, Vt, ao);
  // proj + residual: x2 = x + ao @ w_proj^T + b_proj  (fp32)
  gemm_bf16<1><<<dim3(32, 6), 256, 0, stream>>>(ao, 768, wp, 768, 768,
                                                b_proj, x, 768, x2, 768);
  // LN2
  ln_kernel<<<4096, 256, 0, stream>>>(x2, g2, beta2, h2);
  // fc1 + GELU: f1 = gelu(h2 @ w_fc1^T + b_fc1)  (bf16)
  gemm_bf16<2><<<dim3(32, 24), 256, 0, stream>>>(h2, 768, w1, 768, 768,
                                                 b_fc1, nullptr, 0, f1, 3072);
  // fc2 + residual: out = x2 + f1 @ w_fc2^T + b_fc2  (fp32)
  gemm_bf16<1><<<dim3(32, 6), 256, 0, stream>>>(f1, 3072, w2, 3072, 3072,
                                                b_fc2, x2, 768, (float*)d_out, 768);
}

// Round 3
// 297.204 us; speedup vs baseline: 1.7868x; 1.7687x over previous
//
#include <hip/hip_runtime.h>
#include <hip/hip_bf16.h>
#include <math.h>

// Problem constants: B=1, N=4096, C=768, H=12, HD=64
#define LOG2E 1.44269504088896340736f

typedef short bf16x8 __attribute__((ext_vector_type(8)));
typedef float f32x4 __attribute__((ext_vector_type(4)));

static __device__ __forceinline__ float bf2f(ushort u){
  union { float f; unsigned int u; } x; x.u = ((unsigned int)u) << 16; return x.f;
}
static __device__ __forceinline__ ushort f2bf(float f){
  union { float f; unsigned int u; } x; x.f = f;
  unsigned int r = x.u + 0x7fffu + ((x.u >> 16) & 1u);   // RNE
  return (ushort)(r >> 16);
}
static __device__ __forceinline__ unsigned cvt_pk_bf16(float a, float b){
  unsigned r;
  asm("v_cvt_pk_bf16_f32 %0, %1, %2" : "=v"(r) : "v"(a), "v"(b));
  return r;   // lo = bf16(a), hi = bf16(b)
}
// async global->LDS, 16B per lane; LDS dest = wave-uniform base + lane*16
static __device__ __forceinline__ void gload_lds16(const void* g, void* l){
  __builtin_amdgcn_global_load_lds(
      (const __attribute__((address_space(1))) unsigned int*)g,
      (__attribute__((address_space(3))) unsigned int*)l, 16, 0, 0);
}
#define FK(r) (((r) & 3) | ((((r) >> 3) & 1) << 2))   // K-tile read swizzle

// ---------------- fp32 -> bf16 weight conversion ----------------
__global__ __launch_bounds__(256) void cvt_f32_bf16(const float* __restrict__ src,
                                                    ushort* __restrict__ dst, int n4){
  int i = blockIdx.x * 256 + threadIdx.x;
  if (i < n4){
    float4 v = ((const float4*)src)[i];
    ushort4 o;
    o.x = f2bf(v.x); o.y = f2bf(v.y); o.z = f2bf(v.z); o.w = f2bf(v.w);
    ((ushort4*)dst)[i] = o;
  }
}

// ---------------- LayerNorm (fp32 in -> bf16 out), one block per row of 768 ----------------
__device__ __forceinline__ float block_sum256(float s, float* red){
  #pragma unroll
  for (int off = 32; off; off >>= 1) s += __shfl_xor(s, off, 64);
  int w = threadIdx.x >> 6;
  if ((threadIdx.x & 63) == 0) red[w] = s;
  __syncthreads();
  float tot = red[0] + red[1] + red[2] + red[3];
  __syncthreads();
  return tot;
}

__global__ __launch_bounds__(256) void ln_kernel(const float* __restrict__ x,
                                                 const float* __restrict__ g,
                                                 const float* __restrict__ bta,
                                                 ushort* __restrict__ out){
  __shared__ float red[4];
  int row = blockIdx.x, t = threadIdx.x;
  const float* xr = x + (size_t)row * 768;
  float v0 = xr[t], v1 = xr[t + 256], v2 = xr[t + 512];
  float mu = block_sum256(v0 + v1 + v2, red) * (1.0f / 768.0f);
  float d0 = v0 - mu, d1 = v1 - mu, d2 = v2 - mu;
  float var = block_sum256(d0*d0 + d1*d1 + d2*d2, red) * (1.0f / 768.0f);
  float rs = rsqrtf(var + 1e-5f);
  ushort* orow = out + (size_t)row * 768;
  orow[t]       = f2bf(d0 * rs * g[t]       + bta[t]);
  orow[t + 256] = f2bf(d1 * rs * g[t + 256] + bta[t + 256]);
  orow[t + 512] = f2bf(d2 * rs * g[t + 512] + bta[t + 512]);
}

// ---------------- generic bf16 MFMA GEMM: C[M,N] = A[M,K] * B[N,K]^T ----------------
// 128x128 block tile, BK=64, 4 waves (2x2), each wave 64x64 (4x4 frags of 16x16x32).
// Staging via global_load_lds (16B) with inverse-swizzled SOURCE (T21): LDS[row][s] = G[row][s ^ (row&7)].
// MODE 0: store bf16(C).  MODE 1: store fp32(C + bias + res).  MODE 2: store bf16(gelu(C + bias)).
template<int MODE>
__global__ __launch_bounds__(256) void gemm_bf16(const ushort* __restrict__ A, int lda,
                                                 const ushort* __restrict__ Bm, int ldb,
                                                 int K,
                                                 const float* __restrict__ bias,
                                                 const float* __restrict__ res, int ldr,
                                                 void* __restrict__ out, int ldo){
  __shared__ __align__(16) ushort As[128 * 64];
  __shared__ __align__(16) ushort Bs[128 * 64];
  const int tid = threadIdx.x;
  const int m0 = blockIdx.x * 128, n0 = blockIdx.y * 128;
  const int w = tid >> 6, l = tid & 63;
  const int wm = (w >> 1) * 64, wn = (w & 1) * 64;
  const int lr = l & 15, lg = l >> 4;
  const int lane8 = l >> 3, sl = l & 7;

  f32x4 acc[4][4] = {};

  for (int k0 = 0; k0 < K; k0 += 64){
    #pragma unroll
    for (int j = 0; j < 4; ++j){
      int instr = w * 4 + j;               // 0..15, 1KB each
      int row = instr * 8 + lane8;         // 0..127
      gload_lds16((const char*)A + ((size_t)(m0 + row) * lda + k0) * 2 + ((sl ^ (row & 7)) << 4),
                  (char*)As + instr * 1024);
      gload_lds16((const char*)Bm + ((size_t)(n0 + row) * ldb + k0) * 2 + ((sl ^ (row & 7)) << 4),
                  (char*)Bs + instr * 1024);
    }
    __syncthreads();
    #pragma unroll
    for (int kk = 0; kk < 2; ++kk){
      bf16x8 af[4], bfr[4];
      #pragma unroll
      for (int mi = 0; mi < 4; ++mi){
        int row = wm + mi * 16 + lr;
        int cg = (kk * 4 + lg) ^ (row & 7);
        af[mi] = *(const bf16x8*)(As + row * 64 + cg * 8);
      }
      #pragma unroll
      for (int nj = 0; nj < 4; ++nj){
        int row = wn + nj * 16 + lr;
        int cg = (kk * 4 + lg) ^ (row & 7);
        bfr[nj] = *(const bf16x8*)(Bs + row * 64 + cg * 8);
      }
      #pragma unroll
      for (int mi = 0; mi < 4; ++mi)
        #pragma unroll
        for (int nj = 0; nj < 4; ++nj)
          acc[mi][nj] = __builtin_amdgcn_mfma_f32_16x16x32_bf16(af[mi], bfr[nj], acc[mi][nj], 0, 0, 0);
    }
    __syncthreads();
  }

  // epilogue: D layout row=(lane>>4)*4+reg, col=lane&15 (m89-verified)
  #pragma unroll
  for (int mi = 0; mi < 4; ++mi){
    #pragma unroll
    for (int nj = 0; nj < 4; ++nj){
      #pragma unroll
      for (int r = 0; r < 4; ++r){
        int grow = m0 + wm + mi * 16 + lg * 4 + r;
        int gcol = n0 + wn + nj * 16 + lr;
        float v = acc[mi][nj][r];
        if (MODE == 0){
          ((ushort*)out)[(size_t)grow * ldo + gcol] = f2bf(v);
        } else if (MODE == 1){
          v += bias[gcol] + res[(size_t)grow * ldr + gcol];
          ((float*)out)[(size_t)grow * ldo + gcol] = v;
        } else {
          v += bias[gcol];
          v = 0.5f * v * (1.0f + erff(v * 0.70710678118654752f));  // exact GELU
          ((ushort*)out)[(size_t)grow * ldo + gcol] = f2bf(v);
        }
      }
    }
  }
}

// ---------------- RoPE + QKV reshape: qkv[n][3][h][d] -> Qs/Ks [h][n][d], Vt [h][d][n] ----------------
// Q gets 1/sqrt(HD) * LOG2E folded in (flash softmax works in the exp2 domain).
__global__ __launch_bounds__(384) void rope_kernel(const ushort* __restrict__ qkv,
                                                   const float* __restrict__ fc,
                                                   const float* __restrict__ fs,
                                                   ushort* __restrict__ Qs,
                                                   ushort* __restrict__ Ks,
                                                   ushort* __restrict__ Vt){
  int n = blockIdx.x, t = threadIdx.x;
  int h = t >> 5, p = t & 31;
  float c = fc[(size_t)n * 32 + p], s = fs[(size_t)n * 32 + p];
  const ushort* row = qkv + (size_t)n * 2304;
  const float qscale = 0.125f * LOG2E;
  {
    float t0 = bf2f(row[h * 64 + 2 * p]), t1 = bf2f(row[h * 64 + 2 * p + 1]);
    ushort* dst = Qs + ((size_t)h * 4096 + n) * 64;
    dst[2 * p]     = f2bf((t0 * c - t1 * s) * qscale);
    dst[2 * p + 1] = f2bf((t0 * s + t1 * c) * qscale);
  }
  {
    float t0 = bf2f(row[768 + h * 64 + 2 * p]), t1 = bf2f(row[768 + h * 64 + 2 * p + 1]);
    ushort* dst = Ks + ((size_t)h * 4096 + n) * 64;
    dst[2 * p]     = f2bf(t0 * c - t1 * s);
    dst[2 * p + 1] = f2bf(t0 * s + t1 * c);
  }
  #pragma unroll
  for (int i = 0; i < 2; ++i){
    int idx = t + i * 384;
    int hh = idx >> 6, d = idx & 63;
    Vt[((size_t)hh * 64 + d) * 4096 + n] = row[1536 + idx];
  }
}

// ---------------- flash attention, LDS-staged K/V shared by 4 waves ----------------
// grid (N/64, H), 4 waves/block, each wave owns 16 q-rows (q = q0 + w*16 + (lane&15)).
// 64-key tiles double-buffered in LDS via global_load_lds; swapped QK^T keeps softmax
// in-register (S^T C-layout == PV B-frag after cvt_pk — no shuffles).
__global__ __launch_bounds__(256) void flash_attn(const ushort* __restrict__ Qs,
                                                  const ushort* __restrict__ Ks,
                                                  const ushort* __restrict__ Vt,
                                                  ushort* __restrict__ O){
  __shared__ __align__(16) char smem[32768];   // 2 bufs x (K 8KB + V 8KB)
  int h = blockIdx.y;
  int w = threadIdx.x >> 6, l = threadIdx.x & 63;
  int lr = l & 15, lg = l >> 4;
  int lane8 = l >> 3, sl = l & 7;
  int q0 = blockIdx.x * 64 + w * 16;
  const ushort* Qh = Qs + (size_t)h * (4096 * 64);
  const char* Kh = (const char*)(Ks + (size_t)h * (4096 * 64));
  const char* Vh = (const char*)(Vt + (size_t)h * (64 * 4096));

  bf16x8 qa[2];
  #pragma unroll
  for (int kk = 0; kk < 2; ++kk)
    qa[kk] = *(const bf16x8*)(Qh + (size_t)(q0 + lr) * 64 + kk * 32 + lg * 8);

  // staging: wave w covers rows 16w..16w+15 of the 64-row K and V tiles (2 instrs each)
  int row_a = (w * 2 + 0) * 8 + lane8;          // per-lane source rows
  int row_b = (w * 2 + 1) * 8 + lane8;
  size_t ksrc_a = (size_t)row_a * 128 + ((sl ^ FK(row_a)) << 4);
  size_t ksrc_b = (size_t)row_b * 128 + ((sl ^ FK(row_b)) << 4);
  size_t vsrc_a = (size_t)row_a * 8192 + ((sl ^ (row_a & 7)) << 4);
  size_t vsrc_b = (size_t)row_b * 8192 + ((sl ^ (row_b & 7)) << 4);

  auto stage = [&](int kb, int b){
    char* Kb = smem + b * 16384;
    char* Vb = Kb + 8192;
    gload_lds16(Kh + (size_t)kb * 128 + ksrc_a, Kb + (w * 2 + 0) * 1024);
    gload_lds16(Kh + (size_t)kb * 128 + ksrc_b, Kb + (w * 2 + 1) * 1024);
    gload_lds16(Vh + (size_t)kb * 2 + vsrc_a, Vb + (w * 2 + 0) * 1024);
    gload_lds16(Vh + (size_t)kb * 2 + vsrc_b, Vb + (w * 2 + 1) * 1024);
  };

  f32x4 oacc[4] = {};            // C[d = db*16 + 4lg + r][q = lr]
  float m_prev = -1e30f, lsum = 0.0f;
  const int krow = 8 * (lr >> 2) + (lr & 3);   // permuted K-row base

  stage(0, 0);
  __syncthreads();               // compiler drains vmcnt before barrier

  for (int it = 0; it < 64; ++it){
    int b = it & 1;
    if (it + 1 < 64) stage((it + 1) * 64, b ^ 1);

    const char* Kb = smem + b * 16384;
    const char* Vb = Kb + 8192;

    f32x4 s[4] = {};
    #pragma unroll
    for (int t = 0; t < 4; ++t){
      int row = krow + 4 * (t & 1) + 32 * (t >> 1);
      int fk = FK(row);
      bf16x8 k0 = *(const bf16x8*)(Kb + row * 128 + (((0 + lg) ^ fk) << 4));
      bf16x8 k1 = *(const bf16x8*)(Kb + row * 128 + (((4 + lg) ^ fk) << 4));
      s[t] = __builtin_amdgcn_mfma_f32_16x16x32_bf16(k0, qa[0], s[t], 0, 0, 0);
      s[t] = __builtin_amdgcn_mfma_f32_16x16x32_bf16(k1, qa[1], s[t], 0, 0, 0);
    }
    // row max over this lane's 16 keys, then across the 4 lg-groups (same q = lr)
    float mb = -1e30f;
    #pragma unroll
    for (int r = 0; r < 4; ++r)
      mb = fmaxf(mb, fmaxf(fmaxf(s[0][r], s[1][r]), fmaxf(s[2][r], s[3][r])));
    mb = fmaxf(mb, __shfl_xor(mb, 16, 64));
    mb = fmaxf(mb, __shfl_xor(mb, 32, 64));
    bool defer = (mb - m_prev) <= 8.0f;          // log2 units; P bounded by 256
    float mn = defer ? m_prev : mb;
    if (!__all(defer)){
      float sc = exp2f(m_prev - mn);             // ==1 for deferred lanes
      lsum *= sc;
      #pragma unroll
      for (int db = 0; db < 4; ++db)
        #pragma unroll
        for (int r = 0; r < 4; ++r) oacc[db][r] *= sc;
      m_prev = mn;
    }
    float ps = 0.0f;
    #pragma unroll
    for (int t = 0; t < 4; ++t)
      #pragma unroll
      for (int r = 0; r < 4; ++r){
        float pv = exp2f(s[t][r] - mn);          // Q pre-scaled by log2e
        s[t][r] = pv; ps += pv;
      }
    lsum += ps;                                  // per-lane partial; reduced at end
    #pragma unroll
    for (int kk = 0; kk < 2; ++kk){
      union { unsigned u[4]; bf16x8 v; } pf;
      pf.u[0] = cvt_pk_bf16(s[2*kk][0],   s[2*kk][1]);
      pf.u[1] = cvt_pk_bf16(s[2*kk][2],   s[2*kk][3]);
      pf.u[2] = cvt_pk_bf16(s[2*kk+1][0], s[2*kk+1][1]);
      pf.u[3] = cvt_pk_bf16(s[2*kk+1][2], s[2*kk+1][3]);
      #pragma unroll
      for (int db = 0; db < 4; ++db){
        int d = db * 16 + lr;
        bf16x8 vf = *(const bf16x8*)(Vb + d * 128 + (((kk * 4 + lg) ^ (d & 7)) << 4));
        oacc[db] = __builtin_amdgcn_mfma_f32_16x16x32_bf16(vf, pf.v, oacc[db], 0, 0, 0);
      }
    }
    __syncthreads();             // next tile staged & everyone done with buf b
  }

  lsum += __shfl_xor(lsum, 16, 64);
  lsum += __shfl_xor(lsum, 32, 64);
  float inv = 1.0f / lsum;
  #pragma unroll
  for (int db = 0; db < 4; ++db){
    unsigned o0 = cvt_pk_bf16(oacc[db][0] * inv, oacc[db][1] * inv);
    unsigned o1 = cvt_pk_bf16(oacc[db][2] * inv, oacc[db][3] * inv);
    uint2 ov; ov.x = o0; ov.y = o1;
    *(uint2*)(O + (size_t)(q0 + lr) * 768 + h * 64 + db * 16 + 4 * lg) = ov;
  }
}

// ---------------- launch ----------------
extern "C" void kernel_launch(void* const* d_in, const int* in_sizes, int n_in,
                              void* d_out, int out_size, void* d_ws, size_t ws_size,
                              hipStream_t stream){
  const float* x      = (const float*)d_in[0];
  const float* fcos   = (const float*)d_in[1];
  const float* fsin   = (const float*)d_in[2];
  const float* w_qkv  = (const float*)d_in[3];
  const float* w_proj = (const float*)d_in[4];
  const float* b_proj = (const float*)d_in[5];
  const float* g1     = (const float*)d_in[6];
  const float* beta1  = (const float*)d_in[7];
  const float* g2     = (const float*)d_in[8];
  const float* beta2  = (const float*)d_in[9];
  const float* w_fc1  = (const float*)d_in[10];
  const float* b_fc1  = (const float*)d_in[11];
  const float* w_fc2  = (const float*)d_in[12];
  const float* b_fc2  = (const float*)d_in[13];

  char* ws = (char*)d_ws;
  size_t off = 0;
  auto alloc = [&](size_t bytes) -> char* {
    char* p = ws + off; off += (bytes + 255) & ~(size_t)255; return p;
  };
  ushort* wq  = (ushort*)alloc((size_t)2304 * 768 * 2);
  ushort* wp  = (ushort*)alloc((size_t)768 * 768 * 2);
  ushort* w1  = (ushort*)alloc((size_t)3072 * 768 * 2);
  ushort* w2  = (ushort*)alloc((size_t)768 * 3072 * 2);
  ushort* h1  = (ushort*)alloc((size_t)4096 * 768 * 2);
  ushort* qkv = (ushort*)alloc((size_t)4096 * 2304 * 2);
  ushort* Qs  = (ushort*)alloc((size_t)12 * 4096 * 64 * 2);
  ushort* Ks  = (ushort*)alloc((size_t)12 * 4096 * 64 * 2);
  ushort* Vt  = (ushort*)alloc((size_t)12 * 64 * 4096 * 2);
  ushort* ao  = (ushort*)alloc((size_t)4096 * 768 * 2);
  float*  x2  = (float*) alloc((size_t)4096 * 768 * 4);
  ushort* h2  = (ushort*)alloc((size_t)4096 * 768 * 2);
  ushort* f1  = (ushort*)alloc((size_t)4096 * 3072 * 2);

  // weights -> bf16
  cvt_f32_bf16<<<(2304*768/4 + 255)/256, 256, 0, stream>>>(w_qkv,  wq, 2304*768/4);
  cvt_f32_bf16<<<(768*768/4  + 255)/256, 256, 0, stream>>>(w_proj, wp, 768*768/4);
  cvt_f32_bf16<<<(3072*768/4 + 255)/256, 256, 0, stream>>>(w_fc1,  w1, 3072*768/4);
  cvt_f32_bf16<<<(768*3072/4 + 255)/256, 256, 0, stream>>>(w_fc2,  w2, 768*3072/4);

  // LN1
  ln_kernel<<<4096, 256, 0, stream>>>(x, g1, beta1, h1);
  // QKV: [4096,2304] = h1[4096,768] @ w_qkv[2304,768]^T
  gemm_bf16<0><<<dim3(32, 18), 256, 0, stream>>>(h1, 768, wq, 768, 768,
                                                 nullptr, nullptr, 0, qkv, 2304);
  // RoPE + per-head layouts
  rope_kernel<<<4096, 384, 0, stream>>>(qkv, fcos, fsin, Qs, Ks, Vt);
  // attention
  flash_attn<<<dim3(64, 12), 256, 0, stream>>>(Qs, Ks, Vt, ao);
  // proj + residual: x2 = x + ao @ w_proj^T + b_proj  (fp32)
  gemm_bf16<1><<<dim3(32, 6), 256, 0, stream>>>(ao, 768, wp, 768, 768,
                                                b_proj, x, 768, x2, 768);
  // LN2
  ln_kernel<<<4096, 256, 0, stream>>>(x2, g2, beta2, h2);
  // fc1 + GELU: f1 = gelu(h2 @ w_fc1^T + b_fc1)  (bf16)
  gemm_bf16<2><<<dim3(32, 24), 256, 0, stream>>>(h2, 768, w1, 768, 768,
                                                 b_fc1, nullptr, 0, f1, 3072);
  // fc2 + residual: out = x2 + f1 @ w_fc2^T + b_fc2  (fp32)
  gemm_bf16<1><<<dim3(32, 6), 256, 0, stream>>>(f1, 3072, w2, 3072, 3072,
                                                b_fc2, x2, 768, (float*)d_out, 768);
}